// Round 20
// baseline (67.756 us; speedup 1.0000x reference)
//
#include <hip/hip_runtime.h>
#include <hip/hip_bf16.h>
#include <math.h>

#define NB 8192
#define NG 8
#define NK 1024
#define ND 64
#define GD 512
#define MARGIN 6.0e-4f
#define BIAS 8.0f

typedef __attribute__((ext_vector_type(8))) short short8;
typedef __attribute__((ext_vector_type(4))) float f32x4;

// ws BYTE layout
#define WS_C2_OFF   0                          // f32[8192] exact c2, 32KB
#define WS_C2B_OFF  32768                      // f32[8192] c2 + BIAS, 32KB
#define WS_STG_OFF  65536                      // swizzled bf16 hi/lo staging, 8g*64t*4KB = 2MB
#define WS_HIST_OFF (65536 + 2097152)          // u32[1024]
#define WS_PART_OFF (WS_HIST_OFF + 4096)       // f32[1024]

typedef const __attribute__((address_space(1))) unsigned int glds_src_t;
typedef __attribute__((address_space(3))) unsigned int glds_dst_t;

__device__ inline unsigned umin2(unsigned a, unsigned b) { return a < b ? a : b; }
__device__ inline unsigned umax2(unsigned a, unsigned b) { return a > b ? a : b; }

__device__ inline void bsplit(float v, short& hs, short& ls) {
    __hip_bfloat16 h = __float2bfloat16(v);
    float hf = __bfloat162float(h);
    __hip_bfloat16 l = __float2bfloat16(v - hf);
    hs = *reinterpret_cast<short*>(&h);
    ls = *reinterpret_cast<short*>(&l);
}

__device__ inline float wredsum(float v) {
#pragma unroll
    for (int st = 1; st < 64; st <<= 1) v += __shfl_xor(v, st);
    return v;
}

// ---- prep: c2 exact + biased; tile-contiguous swizzled image ----
// image[g][t] (4KB): [hi 2KB | lo 2KB]; in-tile row = k&15 at row*128;
// granule j stored at j^(row&7)  (row&7 == k&7, identical swizzle bits to r8).
__global__ __launch_bounds__(64) void vq_prep(const float* __restrict__ cb,
                                              float* __restrict__ ws) {
    const int gid = blockIdx.x * 64 + threadIdx.x;    // code id 0..8191
    const int g  = gid >> 10, k = gid & 1023;
    const int t  = k >> 4,   row = k & 15;
    const float* c = cb + (size_t)gid * ND;
    char* base = (char*)ws + WS_STG_OFF + (size_t)(g * 64 + t) * 4096 + row * 128;

    float a0 = 0.f, a1 = 0.f, a2 = 0.f, a3 = 0.f;
#pragma unroll
    for (int j = 0; j < 8; ++j) {                     // granule j: d = 8j..8j+7
        const float4 v0 = reinterpret_cast<const float4*>(c)[2 * j];
        const float4 v1 = reinterpret_cast<const float4*>(c)[2 * j + 1];
        a0 = fmaf(v0.x, v0.x, a0); a1 = fmaf(v0.y, v0.y, a1);
        a2 = fmaf(v0.z, v0.z, a2); a3 = fmaf(v0.w, v0.w, a3);
        a0 = fmaf(v1.x, v1.x, a0); a1 = fmaf(v1.y, v1.y, a1);
        a2 = fmaf(v1.z, v1.z, a2); a3 = fmaf(v1.w, v1.w, a3);
        short h0, l0, h1, l1, h2, l2, h3, l3;
        short h4, l4, h5, l5, h6, l6, h7, l7;
        bsplit(v0.x, h0, l0); bsplit(v0.y, h1, l1);
        bsplit(v0.z, h2, l2); bsplit(v0.w, h3, l3);
        bsplit(v1.x, h4, l4); bsplit(v1.y, h5, l5);
        bsplit(v1.z, h6, l6); bsplit(v1.w, h7, l7);
        short8 hs, ls;
        hs[0] = h0; hs[1] = h1; hs[2] = h2; hs[3] = h3;
        hs[4] = h4; hs[5] = h5; hs[6] = h6; hs[7] = h7;
        ls[0] = l0; ls[1] = l1; ls[2] = l2; ls[3] = l3;
        ls[4] = l4; ls[5] = l5; ls[6] = l6; ls[7] = l7;
        const int off = (j ^ (row & 7)) << 4;
        *reinterpret_cast<short8*>(base + off)        = hs;
        *reinterpret_cast<short8*>(base + 2048 + off) = ls;
    }
    const float c2s = (a0 + a1) + (a2 + a3);
    ((float*)((char*)ws + WS_C2_OFF))[gid]  = c2s;
    ((float*)((char*)ws + WS_C2B_OFF))[gid] = c2s + BIAS;
    if (gid < NK) ((unsigned*)((char*)ws + WS_HIST_OFF))[gid] = 0u;
}

// ---- score+pick fused: barrier-free self-paced waves, per-wave private dbuf;
// ----   6 MFMA + packed argmin (6 tile bits) per 16-code tile; frozen rescue.
__global__ __launch_bounds__(256, 4) void vq_score(const float* __restrict__ z,
                                                   const float* __restrict__ cb,
                                                   float* __restrict__ out,
                                                   float* __restrict__ ws) {
    __shared__ __align__(16) char smem[4][8192];      // per-wave double buffer
    __shared__ float c2sh[1024];                      // biased c2 for this g
    __shared__ int winfo[4][16];
    __shared__ float shred[4];
    const int tid  = threadIdx.x;
    const int w    = tid >> 6;
    const int lane = tid & 63;
    const int lo   = lane & 15, hi = lane >> 4;
    const int g    = blockIdx.y;
    const int rbase = blockIdx.x * 64 + w * 16;       // 16 rows per wave

    const char*  stgg = (const char*)ws + WS_STG_OFF + (size_t)g * 64 * 4096;
    const float* c2g  = (const float*)((const char*)ws + WS_C2_OFF) + g * NK;   // exact (rescue)
    const float* c2bg = (const float*)((const char*)ws + WS_C2B_OFF) + g * NK;  // biased

    // A fragments (16 z-rows): row = rbase + lo, d = ks*32 + hi*8 + e (frozen)
    short8 Ah[2], Al[2];
#pragma unroll
    for (int ks = 0; ks < 2; ++ks) {
        const float* zp = z + (size_t)(rbase + lo) * GD + g * ND + ks * 32 + hi * 8;
        float vv[8];
        *reinterpret_cast<float4*>(&vv[0]) = reinterpret_cast<const float4*>(zp)[0];
        *reinterpret_cast<float4*>(&vv[4]) = reinterpret_cast<const float4*>(zp)[1];
#pragma unroll
        for (int e = 0; e < 8; ++e) {
            short hs, ls;
            bsplit(vv[e], hs, ls);
            Ah[ks][e] = hs;
            Al[ks][e] = ls;
        }
    }

    char* mybuf = &smem[w][0];
    auto STAGE = [&](const char* s, char* d) {        // 4KB tile, linear, 4x1KB
#pragma unroll
        for (int i = 0; i < 4; ++i)
            __builtin_amdgcn_global_load_lds(
                (glds_src_t*)(const void*)(s + i * 1024 + lane * 16),
                (glds_dst_t*)(void*)(d + i * 1024 + lane * 16), 16, 0, 0);
    };

    // prologue: c2 -> LDS (full 1024: each wave stages its 256-float quarter
    // via 4 calls of 64 floats), tiles 0,1 -> private dbuf; one barrier.
#pragma unroll
    for (int i = 0; i < 4; ++i)
        __builtin_amdgcn_global_load_lds(
            (glds_src_t*)(const void*)(c2bg + w * 256 + i * 64 + lane),
            (glds_dst_t*)(void*)(c2sh + w * 256 + i * 64 + lane), 4, 0, 0);
    STAGE(stgg, mybuf);
    STAGE(stgg + 4096, mybuf + 4096);
    __syncthreads();                                  // c2sh visible; drains all vmcnt

    unsigned bestp[4], b2p[4];
#pragma unroll
    for (int q = 0; q < 4; ++q) { bestp[q] = 0xFFFFFFFFu; b2p[q] = 0xFFFFFFFFu; }

    const int rowoff = lo * 128;
    const int swz0 = ((hi ^ (lo & 7)) << 4);
    const int swz1 = (((4 + hi) ^ (lo & 7)) << 4);
    const char* src = stgg + 8192;                    // next tile to stage: 2

    // one 16-code tile: 4 ds_read -> lgkm0 -> stage t+2 -> 6 MFMA -> packed epi -> vmcnt
    auto TILE = [&](int t, const char* buf) {
        const short8 bh0 = *reinterpret_cast<const short8*>(buf + rowoff + swz0);
        const short8 bl0 = *reinterpret_cast<const short8*>(buf + 2048 + rowoff + swz0);
        const short8 bh1 = *reinterpret_cast<const short8*>(buf + rowoff + swz1);
        const short8 bl1 = *reinterpret_cast<const short8*>(buf + 2048 + rowoff + swz1);
        asm volatile("s_waitcnt lgkmcnt(0)" ::: "memory");   // frags in regs
        __builtin_amdgcn_sched_barrier(0);
        if (t < 62) {                                 // stage tile t+2 into this buffer
            STAGE(src, const_cast<char*>(buf));
            src += 4096;
        }
        f32x4 acc = {0.f, 0.f, 0.f, 0.f};
        // frozen per-acc order: ks0 {hh,hl,lh} then ks1 {hh,hl,lh}
        acc = __builtin_amdgcn_mfma_f32_16x16x32_bf16(Ah[0], bh0, acc, 0, 0, 0);
        acc = __builtin_amdgcn_mfma_f32_16x16x32_bf16(Ah[0], bl0, acc, 0, 0, 0);
        acc = __builtin_amdgcn_mfma_f32_16x16x32_bf16(Al[0], bh0, acc, 0, 0, 0);
        acc = __builtin_amdgcn_mfma_f32_16x16x32_bf16(Ah[1], bh1, acc, 0, 0, 0);
        acc = __builtin_amdgcn_mfma_f32_16x16x32_bf16(Ah[1], bl1, acc, 0, 0, 0);
        acc = __builtin_amdgcn_mfma_f32_16x16x32_bf16(Al[1], bh1, acc, 0, 0, 0);

        const float c2v = c2sh[t * 16 + lo];          // LDS broadcast read
#pragma unroll
        for (int q = 0; q < 4; ++q) {                 // packed epi: 5 VALU/score
            const float s = fmaf(-2.0f, acc[q], c2v);
            const unsigned pk = (__float_as_uint(s) & 0xFFFFFFC0u) | (unsigned)t;
            b2p[q]   = umin2(b2p[q], umax2(bestp[q], pk));
            bestp[q] = umin2(bestp[q], pk);
        }
        // self-paced drain: keep tile t+2 in flight, retire t+1
        if (t < 62)       asm volatile("s_waitcnt vmcnt(4)" ::: "memory");
        else if (t == 62) asm volatile("s_waitcnt vmcnt(0)" ::: "memory");
        __builtin_amdgcn_sched_barrier(0);
    };

#pragma unroll 1
    for (int t2 = 0; t2 < 32; ++t2) {
        TILE(2 * t2,     mybuf);                      // even tile, buffer 0
        TILE(2 * t2 + 1, mybuf + 4096);               // odd tile, buffer 1
    }

    // butterfly over the 16 lo-lanes (uint compares, explicit-k tie-break)
#pragma unroll
    for (int q = 0; q < 4; ++q) {
        unsigned pb = bestp[q], p2 = b2p[q];
        int kq  = (int)(pb & 63u) * 16 + lo;
        int kq2 = (int)(p2 & 63u) * 16 + lo;
#pragma unroll
        for (int st = 1; st < 16; st <<= 1) {
            const unsigned ob  = (unsigned)__shfl_xor((int)pb, st);
            const int      obk = __shfl_xor(kq, st);
            const unsigned ob2 = (unsigned)__shfl_xor((int)p2, st);
            const int      ok2 = __shfl_xor(kq2, st);
            const bool bet = (ob < pb) || (ob == pb && obk < kq);
            const unsigned lb  = bet ? pb : ob;        // loser's best
            const int      lk  = bet ? kq : obk;
            const unsigned wb2 = bet ? ob2 : p2;       // winner's second
            const int      wk2 = bet ? ok2 : kq2;
            const bool s2 = (lb < wb2) || (lb == wb2 && lk < wk2);
            p2  = s2 ? lb : wb2;
            kq2 = s2 ? lk : wk2;
            pb  = bet ? ob : pb;
            kq  = bet ? obk : kq;
        }
        if (lo == 0) {
            const float fpb = __uint_as_float(pb & 0xFFFFFFC0u);
            const float fp2 = __uint_as_float(p2 & 0xFFFFFFC0u);
            const int ridx = hi * 4 + q;
            const bool fl = (fp2 - fpb) <= MARGIN;
            winfo[w][ridx] = kq | (kq2 << 10) | (fl ? (1 << 20) : 0);
        }
    }
    asm volatile("s_waitcnt lgkmcnt(0)" ::: "memory");   // winfo visible (intra-wave)
    __builtin_amdgcn_sched_barrier(0);

    // ---- fused pick (frozen serial form; window-2 wredsum rescue) ----
    const float* cgrp = cb + (size_t)g * NK * ND;
    int* wif = &winfo[w][0];
    float esum = 0.f;
#pragma unroll 1
    for (int r = 0; r < 16; ++r) {
        const int info = wif[r];
        const int row  = rbase + r;
        const float zd = z[(size_t)row * GD + g * ND + lane];
        int win = info & 1023;

        if (info & (1 << 20)) {                    // wave-uniform window-2 rescue (frozen)
            const int kalt = (info >> 10) & 1023;
            const float z2 = wredsum(zd * zd);
            const float c1 = cgrp[(size_t)win * ND + lane];
            const float d1 = (z2 + c2g[win]) - 2.0f * wredsum(zd * c1);
            const float c2 = cgrp[(size_t)kalt * ND + lane];
            const float d2 = (z2 + c2g[kalt]) - 2.0f * wredsum(zd * c2);
            if (d2 < d1 || (d2 == d1 && kalt < win)) win = kalt;
            if (lane == 0) wif[r] = win;           // publish resolved (clears flag)
        }

        const float cw = cgrp[(size_t)win * ND + lane];
        out[(size_t)row * GD + g * ND + lane] = zd + (cw - zd);
        const float e = zd - cw;
        esum += e * e;
    }

    // batched index writes + histogram
    asm volatile("s_waitcnt lgkmcnt(0)" ::: "memory");
    __builtin_amdgcn_sched_barrier(0);
    if (lane < 16) {
        const int wv = wif[lane] & 1023;
        out[(size_t)NB * GD + (size_t)(rbase + lane) * NG + g] = (float)wv;
        atomicAdd((unsigned*)((char*)ws + WS_HIST_OFF) + wv, 1u);
    }

    esum = wredsum(esum);
    if (lane == 0) shred[w] = esum;
    __syncthreads();
    if (tid == 0)
        ((float*)((char*)ws + WS_PART_OFF))[blockIdx.y * 128 + blockIdx.x] =
            (shred[0] + shred[1]) + (shred[2] + shred[3]);
}

// ---------------- finalize ----------------
__global__ __launch_bounds__(1024) void vq_final(const float* __restrict__ ws,
                                                 float* __restrict__ out) {
    const int t = threadIdx.x;
    __shared__ float se[1024];
    __shared__ float sc[1024];
    const unsigned cnt = ((const unsigned*)((const char*)ws + WS_HIST_OFF))[t];
    const float usage = (float)cnt * (1.0f / 65536.f);
    se[t] = -usage * logf(usage + 1e-10f);
    const float* part = (const float*)((const char*)ws + WS_PART_OFF);
    sc[t] = part[t];
    __syncthreads();
    for (int st = 512; st > 0; st >>= 1) {
        if (t < st) {
            se[t] += se[t + st];
            sc[t] += sc[t + st];
        }
        __syncthreads();
    }
    if (t == 0) {
        float* scal = out + (size_t)NB * GD + (size_t)NB * NG;
        scal[0] = sc[0] * (1.0f / ((float)NB * NG * ND));  // commitment_loss
        scal[1] = 0.0f;                                    // codebook_loss
        scal[2] = se[0];                                   // entropy
        scal[3] = expf(se[0]);                             // perplexity
    }
}

extern "C" void kernel_launch(void* const* d_in, const int* in_sizes, int n_in,
                              void* d_out, int out_size, void* d_ws, size_t ws_size,
                              hipStream_t stream) {
    const float* z  = (const float*)d_in[0];
    const float* cb = (const float*)d_in[1];
    float* out = (float*)d_out;
    float* ws  = (float*)d_ws;

    hipLaunchKernelGGL(vq_prep,  dim3(128),    dim3(64),   0, stream, cb, ws);
    hipLaunchKernelGGL(vq_score, dim3(128, 8), dim3(256),  0, stream, z, cb, out, ws);
    hipLaunchKernelGGL(vq_final, dim3(1),      dim3(1024), 0, stream, ws, out);
}

// Round 21
// 57.969 us; speedup vs baseline: 1.1688x; 1.1688x over previous
//
#include <hip/hip_runtime.h>
#include <hip/hip_bf16.h>
#include <math.h>

#define NB 8192
#define NG 8
#define NK 1024
#define ND 64
#define GD 512
#define MARGIN 4.0e-4f
#define BIAS 16.0f

typedef __attribute__((ext_vector_type(8))) short short8;
typedef __attribute__((ext_vector_type(4))) float f32x4;

// ws BYTE layout
#define WS_C2_OFF   0                          // f32[8192] exact c2, 32KB
#define WS_C2B_OFF  32768                      // f32[8192] c2 + BIAS, 32KB
#define WS_STG_OFF  65536                      // swizzled bf16 hi/lo staging, 2MB
#define WS_HIST_OFF (65536 + 2097152)          // u32[1024]
#define WS_PART_OFF (WS_HIST_OFF + 4096)       // f32[1024]

typedef const __attribute__((address_space(1))) unsigned int glds_src_t;
typedef __attribute__((address_space(3))) unsigned int glds_dst_t;

__device__ inline unsigned umin2(unsigned a, unsigned b) { return a < b ? a : b; }
__device__ inline unsigned umax2(unsigned a, unsigned b) { return a > b ? a : b; }

__device__ inline void bsplit(float v, short& hs, short& ls) {
    __hip_bfloat16 h = __float2bfloat16(v);
    float hf = __bfloat162float(h);
    __hip_bfloat16 l = __float2bfloat16(v - hf);
    hs = *reinterpret_cast<short*>(&h);
    ls = *reinterpret_cast<short*>(&l);
}

__device__ inline float wredsum(float v) {
#pragma unroll
    for (int st = 1; st < 64; st <<= 1) v += __shfl_xor(v, st);
    return v;
}

// ---- prep: c2 exact + biased; bf16 hi/lo codebook as the XOR-swizzled staging image ----
__global__ __launch_bounds__(64) void vq_prep(const float* __restrict__ cb,
                                              float* __restrict__ ws) {
    const int gid = blockIdx.x * 64 + threadIdx.x;    // code id 0..8191
    const int g  = gid >> 10, k = gid & 1023;
    const int it = k >> 6,   row = k & 63;
    const float* c = cb + (size_t)gid * ND;
    char* base = (char*)ws + WS_STG_OFF + (size_t)(g * 16 + it) * 16384 + row * 128;

    float a0 = 0.f, a1 = 0.f, a2 = 0.f, a3 = 0.f;
#pragma unroll
    for (int j = 0; j < 8; ++j) {                     // granule j: d = 8j..8j+7
        const float4 v0 = reinterpret_cast<const float4*>(c)[2 * j];
        const float4 v1 = reinterpret_cast<const float4*>(c)[2 * j + 1];
        a0 = fmaf(v0.x, v0.x, a0); a1 = fmaf(v0.y, v0.y, a1);
        a2 = fmaf(v0.z, v0.z, a2); a3 = fmaf(v0.w, v0.w, a3);
        a0 = fmaf(v1.x, v1.x, a0); a1 = fmaf(v1.y, v1.y, a1);
        a2 = fmaf(v1.z, v1.z, a2); a3 = fmaf(v1.w, v1.w, a3);
        short h0, l0, h1, l1, h2, l2, h3, l3;
        short h4, l4, h5, l5, h6, l6, h7, l7;
        bsplit(v0.x, h0, l0); bsplit(v0.y, h1, l1);
        bsplit(v0.z, h2, l2); bsplit(v0.w, h3, l3);
        bsplit(v1.x, h4, l4); bsplit(v1.y, h5, l5);
        bsplit(v1.z, h6, l6); bsplit(v1.w, h7, l7);
        short8 hs, ls;
        hs[0] = h0; hs[1] = h1; hs[2] = h2; hs[3] = h3;
        hs[4] = h4; hs[5] = h5; hs[6] = h6; hs[7] = h7;
        ls[0] = l0; ls[1] = l1; ls[2] = l2; ls[3] = l3;
        ls[4] = l4; ls[5] = l5; ls[6] = l6; ls[7] = l7;
        const int off = (j ^ (row & 7)) << 4;
        *reinterpret_cast<short8*>(base + off)        = hs;
        *reinterpret_cast<short8*>(base + 8192 + off) = ls;
    }
    const float c2s = (a0 + a1) + (a2 + a3);
    ((float*)((char*)ws + WS_C2_OFF))[gid]  = c2s;
    ((float*)((char*)ws + WS_C2B_OFF))[gid] = c2s + BIAS;
    if (gid < NK) ((unsigned*)((char*)ws + WS_HIST_OFF))[gid] = 0u;
}

// ---- score+pick fused, r15 structure; packed-u32 argmin (5 ops/score);
// ----   window-2 wredsum rescue FROZEN (the numpy-matching resolver).
__global__ __launch_bounds__(256, 4) void vq_score(const float* __restrict__ z,
                                                   const float* __restrict__ cb,
                                                   float* __restrict__ out,
                                                   float* __restrict__ ws) {
    __shared__ __align__(16) char smem[2][16384];
    __shared__ int winfo[4][16];
    const int tid  = threadIdx.x;
    const int w    = tid >> 6;
    const int lane = tid & 63;
    const int lo   = lane & 15, hi = lane >> 4;
    const int g    = blockIdx.y;
    const int rbase = blockIdx.x * 64 + w * 16;       // 16 rows per wave

    const char*  stg  = (const char*)ws + WS_STG_OFF + (size_t)g * 16 * 16384;
    const float* c2g  = (const float*)((const char*)ws + WS_C2_OFF) + g * NK;   // exact (rescue)
    const float* c2bg = (const float*)((const char*)ws + WS_C2B_OFF) + g * NK;  // biased (k-loop)

    // A fragments (16 z-rows): row = rbase + lo, d = ks*32 + hi*8 + e (frozen)
    short8 Ah[2], Al[2];
#pragma unroll
    for (int ks = 0; ks < 2; ++ks) {
        const float* zp = z + (size_t)(rbase + lo) * GD + g * ND + ks * 32 + hi * 8;
        float vv[8];
        *reinterpret_cast<float4*>(&vv[0]) = reinterpret_cast<const float4*>(zp)[0];
        *reinterpret_cast<float4*>(&vv[4]) = reinterpret_cast<const float4*>(zp)[1];
#pragma unroll
        for (int e = 0; e < 8; ++e) {
            short hs, ls;
            bsplit(vv[e], hs, ls);
            Ah[ks][e] = hs;
            Al[ks][e] = ls;
        }
    }

    // 16 packed argmin streams [n][q]: (score-bits | it), u32
    unsigned bestp[4][4], b2p[4][4];
#pragma unroll
    for (int n = 0; n < 4; ++n)
#pragma unroll
        for (int q = 0; q < 4; ++q) { bestp[n][q] = 0xFFFFFFFFu; b2p[n][q] = 0xFFFFFFFFu; }

    const int rowoff = lo * 128;
    const int swz0 = ((hi ^ (lo & 7)) << 4);
    const int swz1 = (((4 + hi) ^ (lo & 7)) << 4);
    char* lds0 = &smem[0][0];

    const char* src = stg;                            // advances 16KB per staged tile
    auto STAGE = [&](const char* s, unsigned dOff) {
#pragma unroll
        for (int i = 0; i < 4; ++i) {
            const int so = w * 4096 + i * 1024 + lane * 16;
            __builtin_amdgcn_global_load_lds(
                (glds_src_t*)(const void*)(s + so),
                (glds_dst_t*)(void*)(lds0 + dOff + so), 16, 0, 0);
        }
    };

    STAGE(src, 0u);
    src += 16384;
    __syncthreads();

#pragma unroll 1
    for (int it = 0; it < 16; ++it) {
        const int kb = it * 64;
        float c2v[4];
#pragma unroll
        for (int n = 0; n < 4; ++n) c2v[n] = c2bg[kb + n * 16 + lo];

        const unsigned cur = (unsigned)(it & 1) * 16384u;
        if (it < 15) { STAGE(src, cur ^ 16384u); src += 16384; }

        const char* bufc = lds0 + cur;
        f32x4 acc[4] = {{0.f,0.f,0.f,0.f},{0.f,0.f,0.f,0.f},{0.f,0.f,0.f,0.f},{0.f,0.f,0.f,0.f}};
#pragma unroll
        for (int ks = 0; ks < 2; ++ks) {
            short8 bh[4], bl[4];
#pragma unroll
            for (int n = 0; n < 4; ++n) {
                const int off = n * 2048 + rowoff + (ks ? swz1 : swz0);
                bh[n] = *reinterpret_cast<const short8*>(bufc + off);
                bl[n] = *reinterpret_cast<const short8*>(bufc + 8192 + off);
            }
            // per-acc order hh, hl, lh within ks; ks0 before ks1 (frozen)
#pragma unroll
            for (int n = 0; n < 4; ++n)
                acc[n] = __builtin_amdgcn_mfma_f32_16x16x32_bf16(
                    ks ? Ah[1] : Ah[0], bh[n], acc[n], 0, 0, 0);
#pragma unroll
            for (int n = 0; n < 4; ++n)
                acc[n] = __builtin_amdgcn_mfma_f32_16x16x32_bf16(
                    ks ? Ah[1] : Ah[0], bl[n], acc[n], 0, 0, 0);
#pragma unroll
            for (int n = 0; n < 4; ++n)
                acc[n] = __builtin_amdgcn_mfma_f32_16x16x32_bf16(
                    ks ? Al[1] : Al[0], bh[n], acc[n], 0, 0, 0);
        }

        // packed epilogue: 5 VALU/score; scores positive (BIAS), it in low 4 bits
#pragma unroll
        for (int n = 0; n < 4; ++n)
#pragma unroll
            for (int q = 0; q < 4; ++q) {
                const float s = fmaf(-2.0f, acc[n][q], c2v[n]);
                const unsigned pk = (__float_as_uint(s) & 0xFFFFFFF0u) | (unsigned)it;
                b2p[n][q]   = umin2(b2p[n][q], umax2(bestp[n][q], pk));
                bestp[n][q] = umin2(bestp[n][q], pk);
            }
        __syncthreads();
    }

    // end-merge over the 4 n-streams (explicit nb/n2 -> kq,kq2 recoverable),
    // then butterfly over the 16 lo-lanes (uint compares, explicit-k tie-break)
#pragma unroll
    for (int q = 0; q < 4; ++q) {
        unsigned pb = bestp[0][q], p2 = b2p[0][q];
        int nb = 0, n2 = 0;
#pragma unroll
        for (int n = 1; n < 4; ++n) {
            const unsigned cv  = bestp[n][q];
            const unsigned cb2 = b2p[n][q];
            const bool take = cv < pb;                 // ties keep lower n (lower k)
            const unsigned loser  = take ? pb : cv;
            const int      nloser = take ? nb : n;
            pb = take ? cv : pb;
            nb = take ? n : nb;
            if (loser < p2 || (loser == p2 && nloser < n2)) { p2 = loser; n2 = nloser; }
            if (cb2 < p2 || (cb2 == p2 && n < n2))          { p2 = cb2;   n2 = n; }
        }
        int kq  = (int)(pb & 15u) * 64 + nb * 16 + lo;
        int kq2 = (int)(p2 & 15u) * 64 + n2 * 16 + lo;

#pragma unroll
        for (int st = 1; st < 16; st <<= 1) {
            const unsigned ob  = (unsigned)__shfl_xor((int)pb, st);
            const int      obk = __shfl_xor(kq, st);
            const unsigned ob2 = (unsigned)__shfl_xor((int)p2, st);
            const int      ok2 = __shfl_xor(kq2, st);
            const bool bet = (ob < pb) || (ob == pb && obk < kq);
            const unsigned lb  = bet ? pb : ob;        // loser's best
            const int      lk  = bet ? kq : obk;
            const unsigned wb2 = bet ? ob2 : p2;       // winner's second
            const int      wk2 = bet ? ok2 : kq2;
            const bool s2 = (lb < wb2) || (lb == wb2 && lk < wk2);
            p2  = s2 ? lb : wb2;
            kq2 = s2 ? lk : wk2;
            pb  = bet ? ob : pb;
            kq  = bet ? obk : kq;
        }
        if (lo == 0) {
            const float fpb = __uint_as_float(pb & 0xFFFFFFF0u);
            const float fp2 = __uint_as_float(p2 & 0xFFFFFFF0u);
            const int ridx = hi * 4 + q;
            const bool fl = (fp2 - fpb) <= MARGIN;
            winfo[w][ridx] = kq | (kq2 << 10) | (fl ? (1 << 20) : 0);
        }
    }
    asm volatile("s_waitcnt lgkmcnt(0)" ::: "memory");   // winfo visible (intra-wave)
    __builtin_amdgcn_sched_barrier(0);

    // ---- fused pick (r12/r15 serial form verbatim; window-2 wredsum rescue frozen) ----
    const float* cgrp = cb + (size_t)g * NK * ND;
    int* wif = &winfo[w][0];
    float esum = 0.f;
#pragma unroll 1
    for (int r = 0; r < 16; ++r) {
        const int info = wif[r];
        const int row  = rbase + r;
        const float zd = z[(size_t)row * GD + g * ND + lane];
        int win = info & 1023;

        if (info & (1 << 20)) {                    // wave-uniform window-2 rescue (frozen)
            const int kalt = (info >> 10) & 1023;
            const float z2 = wredsum(zd * zd);
            const float c1 = cgrp[(size_t)win * ND + lane];
            const float d1 = (z2 + c2g[win]) - 2.0f * wredsum(zd * c1);
            const float c2 = cgrp[(size_t)kalt * ND + lane];
            const float d2 = (z2 + c2g[kalt]) - 2.0f * wredsum(zd * c2);
            if (d2 < d1 || (d2 == d1 && kalt < win)) win = kalt;
            if (lane == 0) wif[r] = win;           // publish resolved (clears flag)
        }

        const float cw = cgrp[(size_t)win * ND + lane];
        out[(size_t)row * GD + g * ND + lane] = zd + (cw - zd);
        const float e = zd - cw;
        esum += e * e;
    }

    // batched index writes + histogram
    asm volatile("s_waitcnt lgkmcnt(0)" ::: "memory");
    __builtin_amdgcn_sched_barrier(0);
    if (lane < 16) {
        const int wv = wif[lane] & 1023;
        out[(size_t)NB * GD + (size_t)(rbase + lane) * NG + g] = (float)wv;
        atomicAdd((unsigned*)((char*)ws + WS_HIST_OFF) + wv, 1u);
    }

    esum = wredsum(esum);
    __shared__ float sh[4];
    if (lane == 0) sh[w] = esum;
    __syncthreads();
    if (tid == 0)
        ((float*)((char*)ws + WS_PART_OFF))[blockIdx.y * 128 + blockIdx.x] =
            (sh[0] + sh[1]) + (sh[2] + sh[3]);
}

// ---------------- finalize ----------------
__global__ __launch_bounds__(1024) void vq_final(const float* __restrict__ ws,
                                                 float* __restrict__ out) {
    const int t = threadIdx.x;
    __shared__ float se[1024];
    __shared__ float sc[1024];
    const unsigned cnt = ((const unsigned*)((const char*)ws + WS_HIST_OFF))[t];
    const float usage = (float)cnt * (1.0f / 65536.f);
    se[t] = -usage * logf(usage + 1e-10f);
    const float* part = (const float*)((const char*)ws + WS_PART_OFF);
    sc[t] = part[t];
    __syncthreads();
    for (int st = 512; st > 0; st >>= 1) {
        if (t < st) {
            se[t] += se[t + st];
            sc[t] += sc[t + st];
        }
        __syncthreads();
    }
    if (t == 0) {
        float* scal = out + (size_t)NB * GD + (size_t)NB * NG;
        scal[0] = sc[0] * (1.0f / ((float)NB * NG * ND));  // commitment_loss
        scal[1] = 0.0f;                                    // codebook_loss
        scal[2] = se[0];                                   // entropy
        scal[3] = expf(se[0]);                             // perplexity
    }
}

extern "C" void kernel_launch(void* const* d_in, const int* in_sizes, int n_in,
                              void* d_out, int out_size, void* d_ws, size_t ws_size,
                              hipStream_t stream) {
    const float* z  = (const float*)d_in[0];
    const float* cb = (const float*)d_in[1];
    float* out = (float*)d_out;
    float* ws  = (float*)d_ws;

    hipLaunchKernelGGL(vq_prep,  dim3(128),    dim3(64),   0, stream, cb, ws);
    hipLaunchKernelGGL(vq_score, dim3(128, 8), dim3(256),  0, stream, z, cb, out, ws);
    hipLaunchKernelGGL(vq_final, dim3(1),      dim3(1024), 0, stream, ws, out);
}